// Round 17
// baseline (154.637 us; speedup 1.0000x reference)
//
#include <hip/hip_runtime.h>

// Problem dims (fixed): B=4, T=2048, C=64, H=6, D=64, scale = 1/8.
// I/O dtype: float32 (bf16-rounded values). Internal Q/K/Vt/att are bf16.
// Round-17: attn pairs q-tiles (2p, 2p+1) in one block SHARING each staged
// K/V slab: waves 0-1 own tile 2p, waves 2-3 own tile 2p+1, each wave covers
// one 64-j half (4 slices of 16, packed pairwise into K=32 PV MFMAs).
// Staging events per CU halve (25.5 -> 12.75) with NO duplicated reads (the
// split-j sin, r6/r13) and NO cross-barrier registers (the spill trigger,
// r10/r11). Per-wave accumulators = r12 exactly. qkv/proj = r15.

typedef unsigned short u16t;
typedef __attribute__((ext_vector_type(8))) short short8;   // 8 bf16 (MFMA A/B frag)
typedef __attribute__((ext_vector_type(4))) float float4v;  // MFMA C/D frag

#define MFMA16(a, b, c) __builtin_amdgcn_mfma_f32_16x16x32_bf16((a), (b), (c), 0, 0, 0)

union U8 { short8 s; unsigned u[4]; };

__device__ __forceinline__ float fexp2(float x) {  // v_exp_f32: D = 2^S0
  return __builtin_amdgcn_exp2f(x);
}
__device__ __forceinline__ float bf2f(u16t u) {
  return __uint_as_float(((unsigned)u) << 16);
}
__device__ __forceinline__ u16t f2bf(float f) {  // round-nearest-even
  unsigned u = __float_as_uint(f);
  u += 0x7fffu + ((u >> 16) & 1u);
  return (u16t)(u >> 16);
}
__device__ __forceinline__ unsigned bftr(float f) {  // truncated bf16 bits (P only)
  return __float_as_uint(f) >> 16;
}
__device__ __forceinline__ short8 load8_f32_bf16(const float* p) {
  float4 f0 = *(const float4*)p;
  float4 f1 = *(const float4*)(p + 4);
  short8 r;
  r[0] = (short)f2bf(f0.x); r[1] = (short)f2bf(f0.y);
  r[2] = (short)f2bf(f0.z); r[3] = (short)f2bf(f0.w);
  r[4] = (short)f2bf(f1.x); r[5] = (short)f2bf(f1.y);
  r[6] = (short)f2bf(f1.z); r[7] = (short)f2bf(f1.w);
  return r;
}

constexpr int Bb = 4, Tt = 2048, Cc = 64, Hh = 6, Dd = 64;
constexpr int BH = Bb * Hh;         // 24
constexpr int NQT = Tt / 64;        // 32 q-tiles of 64 rows
constexpr int LDT = 72;             // 64-col LDS row stride (144 B)
constexpr int LDV = 136;            // 128-col LDS row stride (272 B)
constexpr int OST = 68;             // f32 O-reduction stride
// exp2-domain: S' = S*log2(e), folded into the Q epilogue scale. No max
// subtraction (f32 overflow needs |S'| > 120; actual |S'| < ~15).
#define QSCALE (0.125f * 1.44269504088896f)

// ---------------------------------------------------------------------------
// Kernel 1: QKV projection via MFMA, in-block weight convert+transpose (r15).
// ---------------------------------------------------------------------------
__global__ __launch_bounds__(256) void qkv_kernel(
    const float* __restrict__ x, const float* __restrict__ y,
    const float* __restrict__ Wq, const float* __restrict__ Wk,
    const float* __restrict__ Wv,
    u16t* __restrict__ Q, u16t* __restrict__ K, u16t* __restrict__ Vt) {
  __shared__ __align__(16) u16t wtq[64 * LDT];
  __shared__ __align__(16) u16t wtk[64 * LDT];
  __shared__ __align__(16) u16t wtv[64 * LDT];

  int bid = blockIdx.x;
  int bh = bid >> 5, tt = bid & 31;
  int b = bh / Hh, h = bh - b * Hh;
  int tid = threadIdx.x;
  int w = tid >> 6, lane = tid & 63;
  int l15 = lane & 15, q4 = lane >> 4;

  {  // stage weights transposed: wt[d][c] = W[c][d], bf16 (float4 reads)
    const float4* wq4 = (const float4*)(Wq + h * 4096);
    const float4* wk4 = (const float4*)(Wk + h * 4096);
    const float4* wv4 = (const float4*)(Wv + h * 4096);
#pragma unroll
    for (int i = 0; i < 4; ++i) {
      int fidx = tid + i * 256;
      float4 qv = wq4[fidx], kv = wk4[fidx], vv = wv4[fidx];
      int base = fidx * 4;
      int c = base >> 6, d0 = base & 63;
      wtq[(d0 + 0) * LDT + c] = f2bf(qv.x);
      wtq[(d0 + 1) * LDT + c] = f2bf(qv.y);
      wtq[(d0 + 2) * LDT + c] = f2bf(qv.z);
      wtq[(d0 + 3) * LDT + c] = f2bf(qv.w);
      wtk[(d0 + 0) * LDT + c] = f2bf(kv.x);
      wtk[(d0 + 1) * LDT + c] = f2bf(kv.y);
      wtk[(d0 + 2) * LDT + c] = f2bf(kv.z);
      wtk[(d0 + 3) * LDT + c] = f2bf(kv.w);
      wtv[(d0 + 0) * LDT + c] = f2bf(vv.x);
      wtv[(d0 + 1) * LDT + c] = f2bf(vv.y);
      wtv[(d0 + 2) * LDT + c] = f2bf(vv.z);
      wtv[(d0 + 3) * LDT + c] = f2bf(vv.w);
    }
  }

  int trow = tt * 64 + w * 16 + l15;
  const float* xrow = x + ((size_t)b * Tt + trow) * Cc;
  const float* yrow = y + ((size_t)b * Tt + trow) * Cc;
  short8 xa[2], ya[2];
#pragma unroll
  for (int kc = 0; kc < 2; ++kc) {
    xa[kc] = load8_f32_bf16(xrow + kc * 32 + q4 * 8);
    ya[kc] = load8_f32_bf16(yrow + kc * 32 + q4 * 8);
  }
  __syncthreads();  // barrier 1: weights staged

  float4v qa4[4], ka4[4], va4[4];
#pragma unroll
  for (int nc = 0; nc < 4; ++nc) {
    qa4[nc] = (float4v){0.f, 0.f, 0.f, 0.f};
    ka4[nc] = (float4v){0.f, 0.f, 0.f, 0.f};
    va4[nc] = (float4v){0.f, 0.f, 0.f, 0.f};
  }
#pragma unroll
  for (int nc = 0; nc < 4; ++nc) {
#pragma unroll
    for (int kc = 0; kc < 2; ++kc) {
      int off = (nc * 16 + l15) * LDT + kc * 32 + q4 * 8;
      short8 bq = *(const short8*)&wtq[off];
      short8 bk = *(const short8*)&wtk[off];
      short8 bv = *(const short8*)&wtv[off];
      qa4[nc] = MFMA16(xa[kc], bq, qa4[nc]);
      ka4[nc] = MFMA16(ya[kc], bk, ka4[nc]);
      va4[nc] = MFMA16(ya[kc], bv, va4[nc]);
    }
  }
  __syncthreads();  // barrier 2: weights read; reuse LDS as store bounce

#pragma unroll
  for (int reg = 0; reg < 4; ++reg) {
    int rloc = w * 16 + q4 * 4 + reg;
#pragma unroll
    for (int nc = 0; nc < 4; ++nc) {
      wtq[rloc * LDT + nc * 16 + l15] = f2bf(qa4[nc][reg] * QSCALE);
      wtk[rloc * LDT + nc * 16 + l15] = f2bf(ka4[nc][reg]);
      wtv[(nc * 16 + l15) * LDT + rloc] = f2bf(va4[nc][reg]);  // transposed V
    }
  }
  __syncthreads();  // barrier 3

  size_t tilebase = ((size_t)bh * Tt + tt * 64) * Dd;
#pragma unroll
  for (int i = 0; i < 2; ++i) {
    int id = tid * 2 + i;
    int row = id >> 3, c8 = id & 7;
    *(uint4*)&Q[tilebase + row * 64 + c8 * 8] = *(const uint4*)&wtq[row * LDT + c8 * 8];
    *(uint4*)&K[tilebase + row * 64 + c8 * 8] = *(const uint4*)&wtk[row * LDT + c8 * 8];
    *(uint4*)&Vt[((size_t)bh * 64 + row) * Tt + tt * 64 + c8 * 8] =
        *(const uint4*)&wtv[row * LDT + c8 * 8];
  }
}

// ---------------------------------------------------------------------------
// Kernel 2: transpose-free causal flash attention, PAIRED q-tiles sharing
// staged BK=128 slabs. Block = (bh, p): tiles 2p and 2p+1; waves {0,1} own
// tile 2p, {2,3} own tile 2p+1; within a pair, wave wp covers slab j-half
// wp (4 slices of 16, packed pairwise into K=32 PV MFMAs). Slabs 0..p.
// Epilogue: 2-round pair reduction + normalize (compile-time reg indices).
// Grid: 24*16 = 384 (p descending), 256 thr, LDS 35.8 KB.
// ---------------------------------------------------------------------------
__global__ __launch_bounds__(256) void attn_kernel(
    const u16t* __restrict__ Q, const u16t* __restrict__ K,
    const u16t* __restrict__ Vt, u16t* __restrict__ att) {
  __shared__ __align__(16) unsigned char smem[128 * LDT * 2 + 64 * LDV * 2];
  u16t* Kl = (u16t*)smem;                    // [128][LDT] bf16
  u16t* Vl = (u16t*)(smem + 128 * LDT * 2);  // [64][LDV]  bf16 ([d][j 0..127])
  float* Ol = (float*)smem;                  // [2][64][OST] f32 overlay (34816 B)
  float* Ll = (float*)(smem + 2 * 64 * OST * 4);  // [2][64] f32 (512 B; total 35328 <= 35840)

  int bid = blockIdx.x;
  int bh = bid % BH;
  int p = 15 - bid / BH;  // big pairs first
  int b = bh / Hh, h = bh - (bh / Hh) * Hh;
  int tid = threadIdx.x;
  int w = tid >> 6;
  int lane = tid & 63;
  int l15 = lane & 15, q4 = lane >> 4;
  int wt = w >> 1;       // 0: tile 2p, 1: tile 2p+1
  int wp = w & 1;        // j-half of each slab owned by this wave
  int qtile = 2 * p + wt;

  // Q B-frags for this wave's tile (4 i-subtiles).
  short8 qf[4][2];
#pragma unroll
  for (int it = 0; it < 4; ++it) {
    const u16t* qb = Q + ((size_t)bh * Tt + qtile * 64 + it * 16 + l15) * Dd;
    qf[it][0] = *(const short8*)(qb + q4 * 8);
    qf[it][1] = *(const short8*)(qb + 32 + q4 * 8);
  }

  float4v O[4][4];  // [i-subtile][nc] partial O over this wave's j half
#pragma unroll
  for (int it = 0; it < 4; ++it)
#pragma unroll
    for (int nc = 0; nc < 4; ++nc) O[it][nc] = (float4v){0.f, 0.f, 0.f, 0.f};
  float l_[4] = {0.f, 0.f, 0.f, 0.f};

  const u16t* Kbh = K + (size_t)bh * Tt * Dd;
  const u16t* Vbh = Vt + (size_t)bh * Dd * Tt;

  for (int bs = 0; bs <= p; ++bs) {
    __syncthreads();  // previous compute's LDS reads done
    {  // plain staging (r12-proven): 1024+1024 chunks of 8 bf16, 4+4/thread
      const u16t* ks = Kbh + (size_t)bs * 8192;  // contiguous 16 KB
      const u16t* vs = Vbh + bs * 128;
#pragma unroll
      for (int i = 0; i < 4; ++i) {
        int id = tid + i * 256;  // 0..1023
        *(uint4*)&Kl[(id >> 3) * LDT + (id & 7) * 8] =
            *(const uint4*)(ks + (size_t)(id >> 3) * 64 + (id & 7) * 8);
        *(uint4*)&Vl[(id >> 4) * LDV + (id & 15) * 8] =
            *(const uint4*)(vs + (size_t)(id >> 4) * Tt + (id & 15) * 8);
      }
    }
    __syncthreads();  // LDS ready

    int gb = bs * 8 + wp * 4;  // global 16-j-unit index of this wave's slice 0
    int tb = qtile * 4;        // global 16-i-unit base of this wave's tile

#pragma unroll
    for (int m = 0; m < 2; ++m) {
      int s0 = wp * 4 + 2 * m;        // slab-local slice pair (s0, s0+1)
      int gs0 = gb + 2 * m, gs1 = gs0 + 1;
      if (gs0 > tb + 3) continue;     // pair beyond all 4 i-subtiles (wave-uniform)

      short8 k0a = *(const short8*)&Kl[(s0 * 16 + l15) * LDT + q4 * 8];
      short8 k0b = *(const short8*)&Kl[(s0 * 16 + l15) * LDT + 32 + q4 * 8];
      short8 k1a = *(const short8*)&Kl[((s0 + 1) * 16 + l15) * LDT + q4 * 8];
      short8 k1b = *(const short8*)&Kl[((s0 + 1) * 16 + l15) * LDT + 32 + q4 * 8];
      short8 vf[4];
#pragma unroll
      for (int nc = 0; nc < 4; ++nc) {  // half0 = slice s0, half1 = slice s0+1
        U8 t;
        *(uint2*)&t.u[0] = *(const uint2*)&Vl[(nc * 16 + l15) * LDV + s0 * 16 + q4 * 4];
        *(uint2*)&t.u[2] = *(const uint2*)&Vl[(nc * 16 + l15) * LDV + (s0 + 1) * 16 + q4 * 4];
        vf[nc] = t.s;
      }

#pragma unroll
      for (int it = 0; it < 4; ++it) {
        int git = tb + it;
        if (gs0 > git) continue;  // wave-uniform: both slices fully masked
        float4v S0 = (float4v){0.f, 0.f, 0.f, 0.f};
        S0 = MFMA16(k0a, qf[it][0], S0);
        S0 = MFMA16(k0b, qf[it][1], S0);
        bool m0 = (gs0 == git);
        float p0[4], p1[4];
#pragma unroll
        for (int reg = 0; reg < 4; ++reg) {
          p0[reg] = (m0 && (q4 * 4 + reg) > l15) ? 0.f : fexp2(S0[reg]);
          l_[it] += p0[reg];
        }
        if (gs1 > git) {
#pragma unroll
          for (int reg = 0; reg < 4; ++reg) p1[reg] = 0.f;
        } else {
          float4v S1 = (float4v){0.f, 0.f, 0.f, 0.f};
          S1 = MFMA16(k1a, qf[it][0], S1);
          S1 = MFMA16(k1b, qf[it][1], S1);
          bool m1 = (gs1 == git);
#pragma unroll
          for (int reg = 0; reg < 4; ++reg) {
            p1[reg] = (m1 && (q4 * 4 + reg) > l15) ? 0.f : fexp2(S1[reg]);
            l_[it] += p1[reg];
          }
        }
        U8 pa;  // slice s0 -> k-slots 0..3, slice s0+1 -> 4..7 (matches vf)
        pa.u[0] = bftr(p0[0]) | (bftr(p0[1]) << 16);
        pa.u[1] = bftr(p0[2]) | (bftr(p0[3]) << 16);
        pa.u[2] = bftr(p1[0]) | (bftr(p1[1]) << 16);
        pa.u[3] = bftr(p1[2]) | (bftr(p1[3]) << 16);
#pragma unroll
        for (int nc = 0; nc < 4; ++nc)
          O[it][nc] = MFMA16(pa.s, vf[nc], O[it][nc]);
      }
    }
  }

  // Reduce l_ over q4 groups; lanes then hold this wave's row-sum (i=l15).
#pragma unroll
  for (int it = 0; it < 4; ++it) {
    l_[it] += __shfl_xor(l_[it], 16);
    l_[it] += __shfl_xor(l_[it], 32);
  }

  // Pair reduction (waves {2wt, 2wt+1} hold same rows, disjoint j): 2 rounds
  // of band rotation with compile-time register indices (runtime index =
  // scratch spill, round-8). Round rr: wave handles itc with (itc>>1)^wp==rr.
  __syncthreads();  // final loop LDS reads done before overlay
#pragma unroll
  for (int rr = 0; rr < 2; ++rr) {
#pragma unroll
    for (int itc = 0; itc < 4; ++itc) {
      if ((((itc >> 1) ^ wp) & 1) == rr) {  // wave-uniform, itc compile-time
#pragma unroll
        for (int nc = 0; nc < 4; ++nc)
#pragma unroll
          for (int reg = 0; reg < 4; ++reg) {
            int addr = (wt * 64 + itc * 16 + q4 * 4 + reg) * OST + nc * 16 + l15;
            if (rr == 0) Ol[addr] = O[itc][nc][reg];
            else         Ol[addr] += O[itc][nc][reg];
          }
        if (q4 == 0) {
          int la = wt * 64 + itc * 16 + l15;
          if (rr == 0) Ll[la] = l_[itc];
          else         Ll[la] += l_[itc];
        }
      }
    }
    __syncthreads();
  }

  // Normalize + store both tiles: 2048 chunks of 8 bf16, 4/thread, coalesced.
#pragma unroll
  for (int i = 0; i < 4; ++i) {
    int id = tid + i * 256;  // 0..1023
    int tile = id >> 9, row = (id >> 3) & 63, c8 = id & 7;
    float inv = 1.0f / Ll[tile * 64 + row];
    const float* orow = &Ol[(tile * 64 + row) * OST + c8 * 8];
    U8 o;
#pragma unroll
    for (int k = 0; k < 4; ++k)
      o.u[k] = f2bf(orow[2 * k] * inv) | ((unsigned)f2bf(orow[2 * k + 1] * inv) << 16);
    int t = (2 * p + tile) * 64 + row;
    *(uint4*)&att[((size_t)b * Tt + t) * (Hh * Dd) + h * Dd + c8 * 8] = *(const uint4*)&o;
  }
}

// ---------------------------------------------------------------------------
// Kernel 3: out = att[8192, 384] @ W_proj[384, 64] + b_proj (r15).
// ---------------------------------------------------------------------------
constexpr int LDP = 392;  // 384+8

__global__ __launch_bounds__(256) void proj_kernel(
    const u16t* __restrict__ att, const float* __restrict__ Wp,
    const float* __restrict__ bp, float* __restrict__ out) {
  __shared__ __align__(16) u16t wpt[64 * LDP];  // 50176 B

  int bid = blockIdx.x;
  int tid = threadIdx.x;
  int w = tid >> 6, lane = tid & 63;
  int l15 = lane & 15, q4 = lane >> 4;

  const float4* wp4 = (const float4*)Wp;
#pragma unroll
  for (int i = 0; i < 24; ++i) {
    int fidx = tid + i * 256;
    float4 v = wp4[fidx];
    int base = fidx * 4;
    int r = base >> 6, c0 = base & 63;
    wpt[(c0 + 0) * LDP + r] = f2bf(v.x);
    wpt[(c0 + 1) * LDP + r] = f2bf(v.y);
    wpt[(c0 + 2) * LDP + r] = f2bf(v.z);
    wpt[(c0 + 3) * LDP + r] = f2bf(v.w);
  }
  __syncthreads();

  int row0 = bid * 64 + w * 16;
  const u16t* arow = att + (size_t)(row0 + l15) * 384;

  float4v acc[4];
#pragma unroll
  for (int nc = 0; nc < 4; ++nc) acc[nc] = (float4v){0.f, 0.f, 0.f, 0.f};

#pragma unroll
  for (int kc = 0; kc < 12; ++kc) {
    short8 a = *(const short8*)(arow + kc * 32 + q4 * 8);
#pragma unroll
    for (int nc = 0; nc < 4; ++nc) {
      short8 bfr = *(const short8*)&wpt[(nc * 16 + l15) * LDP + kc * 32 + q4 * 8];
      acc[nc] = MFMA16(a, bfr, acc[nc]);
    }
  }

  float bv[4];
#pragma unroll
  for (int nc = 0; nc < 4; ++nc) bv[nc] = bp[nc * 16 + l15];
#pragma unroll
  for (int reg = 0; reg < 4; ++reg) {
    int t = row0 + q4 * 4 + reg;
    size_t obase = (size_t)t * 64;
#pragma unroll
    for (int nc = 0; nc < 4; ++nc)
      out[obase + nc * 16 + l15] = acc[nc][reg] + bv[nc];
  }
}

// ---------------------------------------------------------------------------
extern "C" void kernel_launch(void* const* d_in, const int* in_sizes, int n_in,
                              void* d_out, int out_size, void* d_ws, size_t ws_size,
                              hipStream_t stream) {
  const float* x  = (const float*)d_in[0];
  const float* y  = (const float*)d_in[1];
  const float* Wq = (const float*)d_in[2];
  const float* Wk = (const float*)d_in[3];
  const float* Wv = (const float*)d_in[4];
  const float* Wp = (const float*)d_in[5];
  const float* bp = (const float*)d_in[6];
  float* out = (float*)d_out;

  const size_t NBH = (size_t)BH * Tt * Dd;  // 3,145,728 elems
  u16t* Qs   = (u16t*)d_ws;
  u16t* Ks   = Qs + NBH;
  u16t* Vts  = Ks + NBH;
  u16t* attb = Vts + NBH;  // [B,T,H*D] internal bf16

  qkv_kernel<<<BH * NQT, 256, 0, stream>>>(x, y, Wq, Wk, Wv, Qs, Ks, Vts);
  attn_kernel<<<BH * 16, 256, 0, stream>>>(Qs, Ks, Vts, attb);
  proj_kernel<<<(Bb * Tt) / 64, 256, 0, stream>>>(attb, Wp, bp, out);
}